// Round 1
// baseline (670.396 us; speedup 1.0000x reference)
//
#include <hip/hip_runtime.h>
#include <math.h>

#define NFACT 50000
#define NST   2000
#define DFACT 768
#define HC    256
#define EM    500000
#define NK    10
#define NEG   0.2f
#define NHB   196   // 196*256 = 50176 >= 50001 dst slots

__device__ __forceinline__ float lrelu(float x) { return x > 0.f ? x : NEG * x; }

// ---- K1: fused prep.
//  bid <  2000 : statute row -> als[s,2], hsW[s,20] (= per-head hs @ Wc)
//  2000..2005  : V[d,h] = sum_c Wdst[d,h*128+c] * adst[h,c]
//  bid == 2006 : cst[k] = b_rm @ Wc + bc
__global__ __launch_bounds__(256) void k_prep(const float* __restrict__ xs,
                                              const float* __restrict__ Wsrc,
                                              const float* __restrict__ asrc,
                                              const float* __restrict__ Wc,
                                              const float* __restrict__ Wdst,
                                              const float* __restrict__ adst,
                                              const float* __restrict__ b_rm,
                                              const float* __restrict__ bc,
                                              float* __restrict__ als,
                                              float* __restrict__ hsW,
                                              float* __restrict__ V,
                                              float* __restrict__ cst) {
    int b = blockIdx.x, t = threadIdx.x;
    if (b < NST) {
        __shared__ float xrow[256];
        __shared__ float hrow[256];
        __shared__ float wsum[4];
        xrow[t] = xs[b * 256 + t];
        __syncthreads();
        float acc = 0.f;
        for (int d = 0; d < 256; ++d) acc += xrow[d] * Wsrc[d * 256 + t];
        float p = acc * asrc[t];             // t = h*128+c matches asrc [2][128]
        for (int o = 32; o; o >>= 1) p += __shfl_xor(p, o, 64);
        hrow[t] = acc;
        if ((t & 63) == 0) wsum[t >> 6] = p;
        __syncthreads();
        if (t < 20) {                        // t<10: head0,k=t ; else head1,k=t-10
            int h = t / 10, k = t - h * 10;
            float a = 0.f;
            int base = h * 128;
            for (int c = 0; c < 128; ++c) a += hrow[base + c] * Wc[(base + c) * NK + k];
            hsW[b * 20 + t] = a;
        }
        if (t == 0) { als[b * 2 + 0] = wsum[0] + wsum[1]; als[b * 2 + 1] = wsum[2] + wsum[3]; }
    } else if (b < NST + 6) {
        int i = (b - NST) * 256 + t;
        if (i < DFACT * 2) {
            int d = i >> 1, h = i & 1;
            float acc = 0.f;
            for (int c = 0; c < 128; ++c)
                acc += Wdst[d * 256 + h * 128 + c] * adst[h * 128 + c];
            V[d * 2 + h] = acc;
        }
    } else {
        if (t < NK) {
            float a = bc[t];
            for (int ch = 0; ch < HC; ++ch) a += b_rm[ch] * Wc[ch * NK + t];
            cst[t] = a;
        }
    }
}

// ---- K2: bid < NHB : dst-range histogram, LDS atomics only; writes counts chunk + chunk sum.
//          else      : ald = x_fact @ V (16 rows per 1024-thread block; HBM-bound 153.6 MB)
__global__ __launch_bounds__(1024) void k_ald_hist(const float* __restrict__ xf,
                                                   const float* __restrict__ V,
                                                   const int* __restrict__ dst,
                                                   float* __restrict__ ald,
                                                   int* __restrict__ counts,
                                                   int* __restrict__ bsum) {
    int b = blockIdx.x, t = threadIdx.x;
    if (b < NHB) {
        __shared__ int hcnt[256];
        __shared__ int hsum[4];
        if (t < 256) hcnt[t] = 0;
        __syncthreads();
        int base = b << 8;
        for (int e = t; e < EM; e += 1024) {
            unsigned local = (unsigned)(dst[e] - base);
            if (local < 256u) atomicAdd(&hcnt[local], 1);
        }
        __syncthreads();
        if (t < 256) {
            int idx = base + t;
            if (idx <= NFACT) counts[idx] = hcnt[t];
            int v = hcnt[t];
            for (int o = 32; o; o >>= 1) v += __shfl_xor(v, o, 64);
            if ((t & 63) == 0) hsum[t >> 6] = v;
        }
        __syncthreads();
        if (t == 0) bsum[b] = hsum[0] + hsum[1] + hsum[2] + hsum[3];
    } else {
        int lane = t & 63, wid = t >> 6;
        int n = (b - NHB) * 16 + wid;
        const float* row = xf + (size_t)n * DFACT;
        float a0 = 0.f, a1 = 0.f;
        #pragma unroll
        for (int r = 0; r < 3; ++r) {
            int j0 = r * 256 + lane * 4;
            const float4 u = *(const float4*)(row + j0);
            a0 += u.x * V[(j0 + 0) * 2 + 0] + u.y * V[(j0 + 1) * 2 + 0]
                + u.z * V[(j0 + 2) * 2 + 0] + u.w * V[(j0 + 3) * 2 + 0];
            a1 += u.x * V[(j0 + 0) * 2 + 1] + u.y * V[(j0 + 1) * 2 + 1]
                + u.z * V[(j0 + 2) * 2 + 1] + u.w * V[(j0 + 3) * 2 + 1];
        }
        for (int o = 32; o; o >>= 1) { a0 += __shfl_xor(a0, o, 64); a1 += __shfl_xor(a1, o, 64); }
        if (lane == 0) { ald[n * 2 + 0] = a0; ald[n * 2 + 1] = a1; }
    }
}

// ---- K3: fused scan. Each block scans the 196 chunk sums in LDS (cheap), then its own chunk.
__global__ __launch_bounds__(256) void k_scan(const int* __restrict__ counts,
                                              const int* __restrict__ bsum,
                                              int* __restrict__ offs) {
    __shared__ int sb[256];
    __shared__ int sd[256];
    int t = threadIdx.x, b = blockIdx.x;
    sb[t] = (t < NHB) ? bsum[t] : 0;
    __syncthreads();
    for (int o = 1; o < 256; o <<= 1) {
        int v = (t >= o) ? sb[t - o] : 0;
        __syncthreads();
        sb[t] += v;
        __syncthreads();
    }
    int myoff = (b > 0) ? sb[b - 1] : 0;
    int i = b * 256 + t;
    int c = (i <= NFACT) ? counts[i] : 0;
    sd[t] = c;
    __syncthreads();
    for (int o = 1; o < 256; o <<= 1) {
        int v = (t >= o) ? sd[t - o] : 0;
        __syncthreads();
        sd[t] += v;
        __syncthreads();
    }
    if (i <= NFACT) offs[i] = myoff + sd[t] - c;
}

// ---- K4: dst-range scatter, LDS cursors only. Writes src index per CSR slot (4 B/edge).
//          Bucket-internal order is arbitrary — sum is order-independent.
__global__ __launch_bounds__(1024) void k_scat(const int* __restrict__ src,
                                               const int* __restrict__ dst,
                                               const int* __restrict__ offs,
                                               int* __restrict__ perm_s) {
    __shared__ int cur[256];
    int b = blockIdx.x, t = threadIdx.x;
    int base = b << 8;
    if (t < 256) {
        int i = base + t;
        cur[t] = (i <= NFACT) ? offs[i] : 0;
    }
    __syncthreads();
    for (int e = t; e < EM; e += 1024) {
        int d = dst[e];
        unsigned local = (unsigned)(d - base);
        if (local < 256u) {
            int p = atomicAdd(&cur[local], 1);
            perm_s[p] = src[e];
        }
    }
}

// ---- K5: one wave per fact row; lanes 0..19 hold (head,k). Weights recomputed from
//          L1-resident als (16 KB) + wave-uniform ald[n]; denom = own-half running sum.
__global__ __launch_bounds__(256) void k_agg(const float* __restrict__ hsW,
                                             const int* __restrict__ offs,
                                             const int* __restrict__ perm_s,
                                             const float2* __restrict__ als2,
                                             const float2* __restrict__ ald2,
                                             const float* __restrict__ cst,
                                             float* __restrict__ out) {
    int lane = threadIdx.x & 63, wid = threadIdx.x >> 6;
    int n = blockIdx.x * 4 + wid;
    int beg = offs[n], end = offs[n + 1];
    bool live = lane < 20;
    bool h0   = lane < 10;
    float2 aldn = ald2[n];
    float al = h0 ? aldn.x : aldn.y;

    float acc = 0.f, den = 0.f;
    int j = beg;
    for (; j + 4 <= end; j += 4) {
        int sA = perm_s[j + 0], sB = perm_s[j + 1], sC = perm_s[j + 2], sD = perm_s[j + 3];
        float2 aA = als2[sA], aB = als2[sB], aC = als2[sC], aD = als2[sD];
        float hA = live ? hsW[sA * 20 + lane] : 0.f;
        float hB = live ? hsW[sB * 20 + lane] : 0.f;
        float hC = live ? hsW[sC * 20 + lane] : 0.f;
        float hD = live ? hsW[sD * 20 + lane] : 0.f;
        float wA = __expf(lrelu((h0 ? aA.x : aA.y) + al));
        float wB = __expf(lrelu((h0 ? aB.x : aB.y) + al));
        float wC = __expf(lrelu((h0 ? aC.x : aC.y) + al));
        float wD = __expf(lrelu((h0 ? aD.x : aD.y) + al));
        den += (wA + wB) + (wC + wD);
        acc += wA * hA + wB * hB + wC * hC + wD * hD;
    }
    for (; j < end; ++j) {
        int s = perm_s[j];
        float2 a = als2[s];
        float h = live ? hsW[s * 20 + lane] : 0.f;
        float w = __expf(lrelu((h0 ? a.x : a.y) + al));
        den += w;
        acc += w * h;
    }
    float r = acc / (den + 1e-16f);
    float other = __shfl(r, (lane + 10) & 63, 64);   // lane<10 pulls head1 partner
    if (h0) out[n * NK + lane] = r + other + cst[lane];
}

__global__ void k_sentinel(float* __restrict__ out, int n, float val) {
    int i = blockIdx.x * 256 + threadIdx.x;
    if (i < n) out[i] = val;
}

extern "C" void kernel_launch(void* const* d_in, const int* in_sizes, int n_in,
                              void* d_out, int out_size, void* d_ws, size_t ws_size,
                              hipStream_t stream) {
    const float* x_fact    = (const float*)d_in[0];
    const float* x_statute = (const float*)d_in[1];
    const float* Wsrc_rm   = (const float*)d_in[8];
    const float* Wdst_rm   = (const float*)d_in[9];
    const float* asrc_rm   = (const float*)d_in[10];
    const float* adst_rm   = (const float*)d_in[11];
    const float* b_rm      = (const float*)d_in[12];
    const float* Wc        = (const float*)d_in[23];
    const float* bc        = (const float*)d_in[24];
    const int* rm_src      = (const int*)d_in[27];
    const int* rm_dst      = (const int*)d_in[28];
    float* out = (float*)d_out;

    char* w0p = (char*)d_ws;
    char* w = w0p;
    auto carve = [&](size_t bytes) -> void* {
        void* p = (void*)w;
        w += (bytes + 511) & ~(size_t)511;
        return p;
    };
    float* als    = (float*)carve((size_t)NST * 2 * 4);
    float* hsW    = (float*)carve((size_t)NST * 20 * 4);
    float* V      = (float*)carve((size_t)DFACT * 2 * 4);
    float* ald    = (float*)carve((size_t)NFACT * 2 * 4);
    float* cst    = (float*)carve(64);
    int*   counts = (int*)carve((size_t)(NFACT + 1) * 4);
    int*   offs   = (int*)carve((size_t)(NFACT + 1) * 4);
    int*   bsum   = (int*)carve((size_t)NHB * 4);
    int*   perm_s = (int*)carve((size_t)EM * 4);
    if ((size_t)(w - w0p) > ws_size) {
        k_sentinel<<<(out_size + 255) / 256, 256, 0, stream>>>(out, out_size, 2000.f);
        return;
    }

    // K1: statute-side precompute + V + classifier constant (2007 blocks)
    k_prep<<<NST + 7, 256, 0, stream>>>(x_statute, Wsrc_rm, asrc_rm, Wc,
                                        Wdst_rm, adst_rm, b_rm, bc,
                                        als, hsW, V, cst);
    // K2: hist blocks first (overlap with HBM-bound ald blocks)
    k_ald_hist<<<NHB + NFACT / 16, 1024, 0, stream>>>(x_fact, V, rm_dst, ald, counts, bsum);
    // K3: fused two-level scan -> offs
    k_scan<<<NHB, 256, 0, stream>>>(counts, bsum, offs);
    // K4: CSR scatter of src indices (LDS cursors, no global atomics)
    k_scat<<<NHB, 1024, 0, stream>>>(rm_src, rm_dst, offs, perm_s);
    // K5: per-row softmax-weighted aggregation -> classifier output
    k_agg<<<NFACT / 4, 256, 0, stream>>>(hsW, offs, perm_s,
                                         (const float2*)als, (const float2*)ald, cst, out);
}

// Round 2
// 376.280 us; speedup vs baseline: 1.7816x; 1.7816x over previous
//
#include <hip/hip_runtime.h>
#include <math.h>

#define NFACT 50000
#define NST   2000
#define DFACT 768
#define HC    256
#define EM    500000
#define NK    10
#define NEG   0.2f
#define NCHUNK 196   // 196*256 = 50176 >= 50001

__device__ __forceinline__ float lrelu(float x) { return x > 0.f ? x : NEG * x; }

// ---- K1: fused prep.
//  bid <  2000      : statute row -> als[s,2], hsW[s,20] (= per-head hs @ Wc)
//  2000..2005       : V[d,h] = sum_c Wdst[d,h*128+c] * adst[h,c]
//  bid == 2006      : cst[k] = b_rm @ Wc + bc
//  bid >= 2007      : zero counts[0..50000]   (ready for k_hist atomics)
__global__ __launch_bounds__(256) void k_prep(const float* __restrict__ xs,
                                              const float* __restrict__ Wsrc,
                                              const float* __restrict__ asrc,
                                              const float* __restrict__ Wc,
                                              const float* __restrict__ Wdst,
                                              const float* __restrict__ adst,
                                              const float* __restrict__ b_rm,
                                              const float* __restrict__ bc,
                                              float* __restrict__ als,
                                              float* __restrict__ hsW,
                                              float* __restrict__ V,
                                              float* __restrict__ cst,
                                              int* __restrict__ counts) {
    int b = blockIdx.x, t = threadIdx.x;
    if (b < NST) {
        __shared__ float xrow[256];
        __shared__ float hrow[256];
        __shared__ float wsum[4];
        xrow[t] = xs[b * 256 + t];
        __syncthreads();
        float acc = 0.f;
        for (int d = 0; d < 256; ++d) acc += xrow[d] * Wsrc[d * 256 + t];
        float p = acc * asrc[t];             // t = h*128+c matches asrc [2][128]
        for (int o = 32; o; o >>= 1) p += __shfl_xor(p, o, 64);
        hrow[t] = acc;
        if ((t & 63) == 0) wsum[t >> 6] = p;
        __syncthreads();
        if (t < 20) {                        // t<10: head0,k=t ; else head1,k=t-10
            int h = t / 10, k = t - h * 10;
            float a = 0.f;
            int base = h * 128;
            for (int c = 0; c < 128; ++c) a += hrow[base + c] * Wc[(base + c) * NK + k];
            hsW[b * 20 + t] = a;
        }
        if (t == 0) { als[b * 2 + 0] = wsum[0] + wsum[1]; als[b * 2 + 1] = wsum[2] + wsum[3]; }
    } else if (b < NST + 6) {
        int i = (b - NST) * 256 + t;
        if (i < DFACT * 2) {
            int d = i >> 1, h = i & 1;
            float acc = 0.f;
            for (int c = 0; c < 128; ++c)
                acc += Wdst[d * 256 + h * 128 + c] * adst[h * 128 + c];
            V[d * 2 + h] = acc;
        }
    } else if (b == NST + 6) {
        if (t < NK) {
            float a = bc[t];
            for (int ch = 0; ch < HC; ++ch) a += b_rm[ch] * Wc[ch * NK + t];
            cst[t] = a;
        }
    } else {
        int i = (b - (NST + 7)) * 256 + t;
        if (i <= NFACT) counts[i] = 0;
    }
}

// ---- K2: parallel histogram, one edge per thread (global atomics; ~10 hits/counter)
__global__ void k_hist(const int* __restrict__ dst, int* __restrict__ counts) {
    int e = blockIdx.x * 256 + threadIdx.x;
    if (e < EM) atomicAdd(&counts[dst[e]], 1);
}

// ---- K3: per-chunk sums (196 blocks)
__global__ __launch_bounds__(256) void k_scanA(const int* __restrict__ counts,
                                               int* __restrict__ bsum) {
    __shared__ int sd[4];
    int t = threadIdx.x, i = blockIdx.x * 256 + t;
    int c = (i <= NFACT) ? counts[i] : 0;
    int v = c;
    for (int o = 32; o; o >>= 1) v += __shfl_xor(v, o, 64);
    if ((t & 63) == 0) sd[t >> 6] = v;
    __syncthreads();
    if (t == 0) bsum[blockIdx.x] = sd[0] + sd[1] + sd[2] + sd[3];
}

// ---- K4: fused scanB+scanC. Each block redundantly scans the 196 chunk sums in LDS
//          (784 B, free), then scans its own 256-count chunk -> offs + cursor.
__global__ __launch_bounds__(256) void k_scanBC(const int* __restrict__ counts,
                                                const int* __restrict__ bsum,
                                                int* __restrict__ offs,
                                                int* __restrict__ cursor) {
    __shared__ int sb[256];
    __shared__ int sd[256];
    int t = threadIdx.x, b = blockIdx.x;
    sb[t] = (t < NCHUNK) ? bsum[t] : 0;
    __syncthreads();
    for (int o = 1; o < 256; o <<= 1) {
        int v = (t >= o) ? sb[t - o] : 0;
        __syncthreads();
        sb[t] += v;
        __syncthreads();
    }
    int myoff = (b > 0) ? sb[b - 1] : 0;
    int i = b * 256 + t;
    int c = (i <= NFACT) ? counts[i] : 0;
    sd[t] = c;
    __syncthreads();
    for (int o = 1; o < 256; o <<= 1) {
        int v = (t >= o) ? sd[t - o] : 0;
        __syncthreads();
        sd[t] += v;
        __syncthreads();
    }
    if (i <= NFACT) {
        int excl = myoff + sd[t] - c;
        offs[i] = excl;
        cursor[i] = excl;
    }
}

// ---- K5: parallel CSR scatter, one edge per thread (global cursor atomics).
//          Only src index stored (4 B/edge); weights recomputed in k_agg.
__global__ void k_scat(const int* __restrict__ src, const int* __restrict__ dst,
                       int* __restrict__ cursor, int* __restrict__ perm_s) {
    int e = blockIdx.x * 256 + threadIdx.x;
    if (e >= EM) return;
    int d = dst[e];
    int pos = atomicAdd(&cursor[d], 1);
    perm_s[pos] = src[e];
}

// ---- K6: one wave per fact row. Phase 1: ald[n] = x_fact[n] @ V (3 KB coalesced read,
//          butterfly reduce -> sum in all lanes). Phase 2: edge loop; lanes 0..19 hold
//          (head,k); weights recomputed from L1-resident als + in-register al.
__global__ __launch_bounds__(256) void k_agg(const float* __restrict__ xf,
                                             const float* __restrict__ V,
                                             const float* __restrict__ hsW,
                                             const int* __restrict__ offs,
                                             const int* __restrict__ perm_s,
                                             const float2* __restrict__ als2,
                                             const float* __restrict__ cst,
                                             float* __restrict__ out) {
    int lane = threadIdx.x & 63, wid = threadIdx.x >> 6;
    int n = blockIdx.x * 4 + wid;

    // ---- phase 1: ald for this row
    const float* row = xf + (size_t)n * DFACT;
    float a0 = 0.f, a1 = 0.f;
    #pragma unroll
    for (int r = 0; r < 3; ++r) {
        int j0 = r * 256 + lane * 4;
        const float4 u = *(const float4*)(row + j0);
        a0 += u.x * V[(j0 + 0) * 2 + 0] + u.y * V[(j0 + 1) * 2 + 0]
            + u.z * V[(j0 + 2) * 2 + 0] + u.w * V[(j0 + 3) * 2 + 0];
        a1 += u.x * V[(j0 + 0) * 2 + 1] + u.y * V[(j0 + 1) * 2 + 1]
            + u.z * V[(j0 + 2) * 2 + 1] + u.w * V[(j0 + 3) * 2 + 1];
    }
    for (int o = 32; o; o >>= 1) { a0 += __shfl_xor(a0, o, 64); a1 += __shfl_xor(a1, o, 64); }

    // ---- phase 2: softmax-weighted aggregation
    bool live = lane < 20;
    bool h0   = lane < 10;
    float al = h0 ? a0 : a1;
    int beg = offs[n], end = offs[n + 1];

    float acc = 0.f, den = 0.f;
    int j = beg;
    for (; j + 4 <= end; j += 4) {
        int sA = perm_s[j + 0], sB = perm_s[j + 1], sC = perm_s[j + 2], sD = perm_s[j + 3];
        float2 aA = als2[sA], aB = als2[sB], aC = als2[sC], aD = als2[sD];
        float hA = live ? hsW[sA * 20 + lane] : 0.f;
        float hB = live ? hsW[sB * 20 + lane] : 0.f;
        float hC = live ? hsW[sC * 20 + lane] : 0.f;
        float hD = live ? hsW[sD * 20 + lane] : 0.f;
        float wA = __expf(lrelu((h0 ? aA.x : aA.y) + al));
        float wB = __expf(lrelu((h0 ? aB.x : aB.y) + al));
        float wC = __expf(lrelu((h0 ? aC.x : aC.y) + al));
        float wD = __expf(lrelu((h0 ? aD.x : aD.y) + al));
        den += (wA + wB) + (wC + wD);
        acc += wA * hA + wB * hB + wC * hC + wD * hD;
    }
    for (; j < end; ++j) {
        int s = perm_s[j];
        float2 a = als2[s];
        float h = live ? hsW[s * 20 + lane] : 0.f;
        float w = __expf(lrelu((h0 ? a.x : a.y) + al));
        den += w;
        acc += w * h;
    }
    float r = acc / (den + 1e-16f);
    float other = __shfl(r, (lane + 10) & 63, 64);   // lane<10 pulls head1 partner
    if (h0) out[n * NK + lane] = r + other + cst[lane];
}

__global__ void k_sentinel(float* __restrict__ out, int n, float val) {
    int i = blockIdx.x * 256 + threadIdx.x;
    if (i < n) out[i] = val;
}

extern "C" void kernel_launch(void* const* d_in, const int* in_sizes, int n_in,
                              void* d_out, int out_size, void* d_ws, size_t ws_size,
                              hipStream_t stream) {
    const float* x_fact    = (const float*)d_in[0];
    const float* x_statute = (const float*)d_in[1];
    const float* Wsrc_rm   = (const float*)d_in[8];
    const float* Wdst_rm   = (const float*)d_in[9];
    const float* asrc_rm   = (const float*)d_in[10];
    const float* adst_rm   = (const float*)d_in[11];
    const float* b_rm      = (const float*)d_in[12];
    const float* Wc        = (const float*)d_in[23];
    const float* bc        = (const float*)d_in[24];
    const int* rm_src      = (const int*)d_in[27];
    const int* rm_dst      = (const int*)d_in[28];
    float* out = (float*)d_out;

    char* w0p = (char*)d_ws;
    char* w = w0p;
    auto carve = [&](size_t bytes) -> void* {
        void* p = (void*)w;
        w += (bytes + 511) & ~(size_t)511;
        return p;
    };
    float* als    = (float*)carve((size_t)NST * 2 * 4);
    float* hsW    = (float*)carve((size_t)NST * 20 * 4);
    float* V      = (float*)carve((size_t)DFACT * 2 * 4);
    float* cst    = (float*)carve(64);
    int*   counts = (int*)carve((size_t)(NFACT + 1) * 4);
    int*   offs   = (int*)carve((size_t)(NFACT + 1) * 4);
    int*   cursor = (int*)carve((size_t)(NFACT + 1) * 4);
    int*   bsum   = (int*)carve((size_t)NCHUNK * 4);
    int*   perm_s = (int*)carve((size_t)EM * 4);
    if ((size_t)(w - w0p) > ws_size) {
        k_sentinel<<<(out_size + 255) / 256, 256, 0, stream>>>(out, out_size, 2000.f);
        return;
    }

    // K1: statute precompute + V + cst + counts-zeroing (2203 blocks, 1 launch)
    k_prep<<<NST + 7 + NCHUNK, 256, 0, stream>>>(x_statute, Wsrc_rm, asrc_rm, Wc,
                                                 Wdst_rm, adst_rm, b_rm, bc,
                                                 als, hsW, V, cst, counts);
    // K2: parallel histogram (one edge per thread)
    k_hist<<<(EM + 255) / 256, 256, 0, stream>>>(rm_dst, counts);
    // K3: chunk sums
    k_scanA<<<NCHUNK, 256, 0, stream>>>(counts, bsum);
    // K4: fused block-offset + intra-chunk scan -> offs, cursor
    k_scanBC<<<NCHUNK, 256, 0, stream>>>(counts, bsum, offs, cursor);
    // K5: parallel CSR scatter (one edge per thread)
    k_scat<<<(EM + 255) / 256, 256, 0, stream>>>(rm_src, rm_dst, cursor, perm_s);
    // K6: fused ald + softmax-weighted aggregation -> classifier output
    k_agg<<<NFACT / 4, 256, 0, stream>>>(x_fact, V, hsW, offs, perm_s,
                                         (const float2*)als, cst, out);
}